// Round 8
// baseline (6832.649 us; speedup 1.0000x reference)
//
#include <hip/hip_runtime.h>
#include <hip/hip_bf16.h>

#define NLAYERS 6
#define B_ 4
#define L_ 1024
#define DM_ 512
#define DI_ 1024
#define NH_ 16
#define HD_ 64
#define NS_ 16
#define CONVD_ 1056
#define DPROJ_ 2096
#define DFF_ 2048
#define ROWS_ (B_*L_)
#define EPS_ 1e-5f

// ---------------- block reduction ----------------
__device__ __forceinline__ float block_reduce_sum(float v){
    __shared__ float sm[8];
    #pragma unroll
    for (int off = 32; off > 0; off >>= 1) v += __shfl_xor(v, off);
    int lane = threadIdx.x & 63, wid = threadIdx.x >> 6;
    if (lane == 0) sm[wid] = v;
    __syncthreads();
    if (threadIdx.x == 0){
        float t = 0.f;
        int nw = blockDim.x >> 6;
        for (int i = 0; i < nw; i++) t += sm[i];
        sm[0] = t;
    }
    __syncthreads();
    return sm[0];
}

// ---------------- copy x -> X ----------------
__global__ void copy_kernel(const float* __restrict__ x, float* __restrict__ X, int n){
    int i = blockIdx.x * blockDim.x + threadIdx.x;
    if (i < n) X[i] = x[i];
}

// ---------------- per-row inverse-RMS of X[ROWS][512] ----------------
__global__ __launch_bounds__(64) void rowscale_kernel(const float* __restrict__ X,
                                                      float* __restrict__ rs){
    int row = blockIdx.x, lane = threadIdx.x;
    const float* xr = X + (size_t)row * DM_;
    float ss = 0.f;
    #pragma unroll
    for (int i = 0; i < DM_ / 64; i++){ float v = xr[lane + 64 * i]; ss += v * v; }
    #pragma unroll
    for (int off = 32; off > 0; off >>= 1) ss += __shfl_xor(ss, off);
    if (lane == 0) rs[row] = rsqrtf(ss / (float)DM_ + EPS_);
}

// ---------------- final rmsnorm -> f32 out ----------------
__global__ void finalnorm_kernel(const float* __restrict__ in, const float* __restrict__ w,
                                 float* __restrict__ out){
    int row = blockIdx.x;
    const float* xr = in + (size_t)row * DM_;
    float ss = 0.f;
    for (int c = threadIdx.x; c < DM_; c += blockDim.x){ float v = xr[c]; ss += v * v; }
    float tot = block_reduce_sum(ss);
    float rsv = rsqrtf(tot / (float)DM_ + EPS_);
    float* orow = out + (size_t)row * DM_;
    for (int c = threadIdx.x; c < DM_; c += blockDim.x)
        orow[c] = xr[c] * rsv * w[c];
}

// ---------------- GEMM: C[M][N](ldc) = (A(lda)*rs[m]?*wvec[k]?) @ W[N,K]^T (+bias)(+gelu)(+resid) ----------------
__global__ __launch_bounds__(256) void gemm_kernel(
    const float* __restrict__ A, int lda,
    const float* __restrict__ rs, const float* __restrict__ wvec,
    const float* __restrict__ W,
    const float* __restrict__ bias, const float* __restrict__ resid, int ldr,
    float* __restrict__ C, int ldc, int M, int N, int K, int act)
{
    const int BK = 16, ROWP = 68;
    __shared__ float As[BK][ROWP];
    __shared__ float Bs[BK][ROWP];
    int tid = threadIdx.x;
    int n0 = blockIdx.x * 64, m0 = blockIdx.y * 64;
    int lr = tid >> 2;          // 0..63
    int lk = (tid & 3) * 4;     // 0,4,8,12
    int row0 = (tid >> 4) * 4, col0 = (tid & 15) * 4;
    float acc[4][4] = {};

    for (int k0 = 0; k0 < K; k0 += BK){
        float4 av = *reinterpret_cast<const float4*>(&A[(size_t)(m0 + lr) * lda + k0 + lk]);
        float sc = rs ? rs[m0 + lr] : 1.f;
        if (wvec){
            const float4 wv4 = *reinterpret_cast<const float4*>(&wvec[k0 + lk]);
            av.x *= wv4.x; av.y *= wv4.y; av.z *= wv4.z; av.w *= wv4.w;
        }
        As[lk + 0][lr] = av.x * sc; As[lk + 1][lr] = av.y * sc;
        As[lk + 2][lr] = av.z * sc; As[lk + 3][lr] = av.w * sc;
        int n = n0 + lr;
        float4 wv = make_float4(0.f, 0.f, 0.f, 0.f);
        if (n < N) wv = *reinterpret_cast<const float4*>(&W[(size_t)n * K + k0 + lk]);
        Bs[lk + 0][lr] = wv.x; Bs[lk + 1][lr] = wv.y; Bs[lk + 2][lr] = wv.z; Bs[lk + 3][lr] = wv.w;
        __syncthreads();
        #pragma unroll
        for (int k = 0; k < BK; k++){
            float a0 = As[k][row0 + 0], a1 = As[k][row0 + 1], a2 = As[k][row0 + 2], a3 = As[k][row0 + 3];
            float b0 = Bs[k][col0 + 0], b1 = Bs[k][col0 + 1], b2 = Bs[k][col0 + 2], b3 = Bs[k][col0 + 3];
            acc[0][0] += a0 * b0; acc[0][1] += a0 * b1; acc[0][2] += a0 * b2; acc[0][3] += a0 * b3;
            acc[1][0] += a1 * b0; acc[1][1] += a1 * b1; acc[1][2] += a1 * b2; acc[1][3] += a1 * b3;
            acc[2][0] += a2 * b0; acc[2][1] += a2 * b1; acc[2][2] += a2 * b2; acc[2][3] += a2 * b3;
            acc[3][0] += a3 * b0; acc[3][1] += a3 * b1; acc[3][2] += a3 * b2; acc[3][3] += a3 * b3;
        }
        __syncthreads();
    }

    #pragma unroll
    for (int i = 0; i < 4; i++){
        int m = m0 + row0 + i;
        #pragma unroll
        for (int j = 0; j < 4; j++){
            int n = n0 + col0 + j;
            if (n < N){
                float c = acc[i][j];
                if (bias) c += bias[n];
                if (act == 1) c = 0.5f * c * (1.f + erff(c * 0.70710678118654752f));
                if (resid) c += resid[(size_t)m * ldr + n];
                C[(size_t)m * ldc + n] = c;
            }
        }
    }
}

// ---------------- conv+silu for the 32 B/C channels -> BCc[ROWS][32] ----------------
__global__ void bcconv_kernel(const float* __restrict__ ZX, const float* __restrict__ cw,
                              const float* __restrict__ cb, float* __restrict__ BCc){
    int idx = blockIdx.x * blockDim.x + threadIdx.x;
    if (idx >= ROWS_ * 32) return;
    int j = idx & 31;
    int row = idx >> 5;
    int l = row & (L_ - 1);
    float acc = cb[DI_ + j];
    #pragma unroll
    for (int k = 0; k < 4; k++){
        int lt = l + k - 3;
        if (lt >= 0)
            acc += ZX[(size_t)(row + k - 3) * DPROJ_ + (DI_ + DI_) + j] * cw[(DI_ + j) * 4 + k];
    }
    BCc[idx] = acc / (1.f + expf(-acc));
}

// ---------------- dt = softplus(raw + dt_bias); dA = exp(-exp(A_log)*dt) ----------------
__global__ void dt_kernel(const float* __restrict__ ZX, const float* __restrict__ dtb,
                          const float* __restrict__ Alog, float* __restrict__ DT,
                          float* __restrict__ DA){
    int idx = blockIdx.x * blockDim.x + threadIdx.x;
    if (idx >= ROWS_ * NH_) return;
    int h = idx & 15; int row = idx >> 4;
    float v = ZX[(size_t)row * DPROJ_ + (DPROJ_ - NH_) + h] + dtb[h];
    float dtv = (v > 20.f) ? v : log1pf(expf(v));
    DT[idx] = dtv;
    DA[idx] = expf(-expf(Alog[h]) * dtv);
}

// ---------------- SSM scan with fused x-conv; y written over the xBC slot of ZX ----------------
__global__ __launch_bounds__(64) void scan_kernel(float* __restrict__ ZX,
                                                  const float* __restrict__ BCc,
                                                  const float* __restrict__ DT,
                                                  const float* __restrict__ DA,
                                                  const float* __restrict__ cw,
                                                  const float* __restrict__ cb,
                                                  const float* __restrict__ Dh){
    int bh = blockIdx.x; int b = bh >> 4; int h = bh & 15; int p = threadIdx.x;
    int c = h * HD_ + p;
    float cw0 = cw[c * 4 + 0], cw1 = cw[c * 4 + 1], cw2 = cw[c * 4 + 2], cw3 = cw[c * 4 + 3];
    float cbc = cb[c];
    float Dv = Dh[h];
    float s[16];
    #pragma unroll
    for (int n = 0; n < 16; n++) s[n] = 0.f;
    float w0 = 0.f, w1 = 0.f, w2 = 0.f;
    size_t colx = (size_t)DI_ + c;

    for (int t = 0; t < L_; t++){
        int row = b * L_ + t;
        size_t rowoff = (size_t)row * DPROJ_;
        float cur = ZX[rowoff + colx];
        float pre = cbc + cw0 * w0 + cw1 * w1 + cw2 * w2 + cw3 * cur;
        float xc = pre / (1.f + expf(-pre));
        w0 = w1; w1 = w2; w2 = cur;
        float dtv = DT[row * NH_ + h];
        float dav = DA[row * NH_ + h];
        float bc[32];
        const float4* bp = reinterpret_cast<const float4*>(BCc + (size_t)row * 32);
        #pragma unroll
        for (int i = 0; i < 8; i++){
            float4 v = bp[i];
            bc[4 * i + 0] = v.x; bc[4 * i + 1] = v.y; bc[4 * i + 2] = v.z; bc[4 * i + 3] = v.w;
        }
        float coef = dtv * xc;
        float y = 0.f;
        #pragma unroll
        for (int n = 0; n < 16; n++){
            s[n] = s[n] * dav + coef * bc[n];
            y += s[n] * bc[16 + n];
        }
        ZX[rowoff + colx] = fmaf(Dv, xc, y);
    }
}

// ---------------- gated rmsnorm in place on ZX ----------------
__global__ void gatenorm_kernel(float* __restrict__ ZX, const float* __restrict__ gw){
    int row = blockIdx.x;
    float* zr = ZX + (size_t)row * DPROJ_;
    float* yr = zr + DI_;
    float ss = 0.f;
    for (int cc = threadIdx.x; cc < DI_; cc += blockDim.x){
        float z = zr[cc];
        float v = yr[cc] * (z / (1.f + expf(-z)));
        yr[cc] = v;
        ss += v * v;
    }
    float tot = block_reduce_sum(ss);
    float rsv = rsqrtf(tot / (float)DI_ + EPS_);
    for (int cc = threadIdx.x; cc < DI_; cc += blockDim.x)
        yr[cc] = yr[cc] * rsv * gw[cc];
}

extern "C" void kernel_launch(void* const* d_in, const int* in_sizes, int n_in,
                              void* d_out, int out_size, void* d_ws, size_t ws_size,
                              hipStream_t stream){
    const float* x_in        = (const float*)d_in[0];
    const float* in_proj_w   = (const float*)d_in[1];
    const float* conv_w      = (const float*)d_in[2];
    const float* conv_b      = (const float*)d_in[3];
    const float* dt_bias     = (const float*)d_in[4];
    const float* A_log       = (const float*)d_in[5];
    const float* D_ssm       = (const float*)d_in[6];
    const float* gnorm_w     = (const float*)d_in[7];
    const float* out_proj_w  = (const float*)d_in[8];
    const float* ffn_w1      = (const float*)d_in[9];
    const float* ffn_b1      = (const float*)d_in[10];
    const float* ffn_w2      = (const float*)d_in[11];
    const float* ffn_b2      = (const float*)d_in[12];
    const float* norm_mamba_w= (const float*)d_in[13];
    const float* norm_ffn_w  = (const float*)d_in[14];
    const float* final_norm_w= (const float*)d_in[15];

    // ---- workspace layout: ~41.8 MiB (fits; verified by R6 probe) ----
    float* X   = (float*)d_ws;                        // ROWS*DM
    float* RS  = X   + (size_t)ROWS_ * DM_;           // ROWS
    float* BCc = RS  + ROWS_;                         // ROWS*32
    float* DT  = BCc + (size_t)ROWS_ * 32;            // ROWS*16
    float* DA  = DT  + (size_t)ROWS_ * NH_;           // ROWS*16
    float* ZX  = DA  + (size_t)ROWS_ * NH_;           // ROWS*DPROJ (reused as FFN hidden)

    copy_kernel<<<(ROWS_ * DM_ + 255) / 256, 256, 0, stream>>>(x_in, X, ROWS_ * DM_);

    for (int l = 0; l < NLAYERS; l++){
        rowscale_kernel<<<ROWS_, 64, 0, stream>>>(X, RS);

        dim3 g1((DPROJ_ + 63) / 64, ROWS_ / 64);
        gemm_kernel<<<g1, 256, 0, stream>>>(X, DM_, RS, norm_mamba_w + l * DM_,
                                            in_proj_w + (size_t)l * DPROJ_ * DM_,
                                            nullptr, nullptr, 0,
                                            ZX, DPROJ_, ROWS_, DPROJ_, DM_, 0);

        bcconv_kernel<<<(ROWS_ * 32 + 255) / 256, 256, 0, stream>>>(
            ZX, conv_w + (size_t)l * CONVD_ * 4, conv_b + (size_t)l * CONVD_, BCc);

        dt_kernel<<<(ROWS_ * NH_ + 255) / 256, 256, 0, stream>>>(
            ZX, dt_bias + (size_t)l * NH_, A_log + (size_t)l * NH_, DT, DA);

        scan_kernel<<<B_ * NH_, 64, 0, stream>>>(ZX, BCc, DT, DA,
                                                 conv_w + (size_t)l * CONVD_ * 4,
                                                 conv_b + (size_t)l * CONVD_,
                                                 D_ssm + (size_t)l * NH_);

        gatenorm_kernel<<<ROWS_, 256, 0, stream>>>(ZX, gnorm_w + (size_t)l * DI_);

        dim3 g2((DM_ + 63) / 64, ROWS_ / 64);
        gemm_kernel<<<g2, 256, 0, stream>>>(ZX + DI_, DPROJ_, nullptr, nullptr,
                                            out_proj_w + (size_t)l * DM_ * DI_,
                                            nullptr, X, DM_,
                                            X, DM_, ROWS_, DM_, DI_, 0);

        rowscale_kernel<<<ROWS_, 64, 0, stream>>>(X, RS);

        dim3 g3((DFF_ + 63) / 64, ROWS_ / 64);
        gemm_kernel<<<g3, 256, 0, stream>>>(X, DM_, RS, norm_ffn_w + l * DM_,
                                            ffn_w1 + (size_t)l * DFF_ * DM_,
                                            ffn_b1 + (size_t)l * DFF_, nullptr, 0,
                                            ZX, DFF_, ROWS_, DFF_, DM_, 1);

        gemm_kernel<<<g2, 256, 0, stream>>>(ZX, DFF_, nullptr, nullptr,
                                            ffn_w2 + (size_t)l * DM_ * DFF_,
                                            ffn_b2 + (size_t)l * DM_, X, DM_,
                                            X, DM_, ROWS_, DM_, DFF_, 0);
    }

    finalnorm_kernel<<<ROWS_, 256, 0, stream>>>(X, final_norm_w, (float*)d_out);
}

// Round 9
// 4152.818 us; speedup vs baseline: 1.6453x; 1.6453x over previous
//
#include <hip/hip_runtime.h>
#include <hip/hip_bf16.h>

#define NLAYERS 6
#define B_ 4
#define L_ 1024
#define DM_ 512
#define DI_ 1024
#define NH_ 16
#define HD_ 64
#define NS_ 16
#define CONVD_ 1056
#define DPROJ_ 2096
#define DFF_ 2048
#define ROWS_ (B_*L_)
#define EPS_ 1e-5f
#define NCHUNK_ 16
#define CLEN_ 64

// ---------------- block reduction ----------------
__device__ __forceinline__ float block_reduce_sum(float v){
    __shared__ float sm[8];
    #pragma unroll
    for (int off = 32; off > 0; off >>= 1) v += __shfl_xor(v, off);
    int lane = threadIdx.x & 63, wid = threadIdx.x >> 6;
    if (lane == 0) sm[wid] = v;
    __syncthreads();
    if (threadIdx.x == 0){
        float t = 0.f;
        int nw = blockDim.x >> 6;
        for (int i = 0; i < nw; i++) t += sm[i];
        sm[0] = t;
    }
    __syncthreads();
    return sm[0];
}

// ---------------- copy x -> X ----------------
__global__ void copy_kernel(const float* __restrict__ x, float* __restrict__ X, int n){
    int i = blockIdx.x * blockDim.x + threadIdx.x;
    if (i < n) X[i] = x[i];
}

// ---------------- per-row inverse-RMS of X[ROWS][512] ----------------
__global__ __launch_bounds__(64) void rowscale_kernel(const float* __restrict__ X,
                                                      float* __restrict__ rs){
    int row = blockIdx.x, lane = threadIdx.x;
    const float* xr = X + (size_t)row * DM_;
    float ss = 0.f;
    #pragma unroll
    for (int i = 0; i < DM_ / 64; i++){ float v = xr[lane + 64 * i]; ss += v * v; }
    #pragma unroll
    for (int off = 32; off > 0; off >>= 1) ss += __shfl_xor(ss, off);
    if (lane == 0) rs[row] = rsqrtf(ss / (float)DM_ + EPS_);
}

// ---------------- final rmsnorm -> f32 out ----------------
__global__ void finalnorm_kernel(const float* __restrict__ in, const float* __restrict__ w,
                                 float* __restrict__ out){
    int row = blockIdx.x;
    const float* xr = in + (size_t)row * DM_;
    float ss = 0.f;
    for (int c = threadIdx.x; c < DM_; c += blockDim.x){ float v = xr[c]; ss += v * v; }
    float tot = block_reduce_sum(ss);
    float rsv = rsqrtf(tot / (float)DM_ + EPS_);
    float* orow = out + (size_t)row * DM_;
    for (int c = threadIdx.x; c < DM_; c += blockDim.x)
        orow[c] = xr[c] * rsv * w[c];
}

// ---------------- GEMM: C[M][N](ldc) = (A(lda)*rs[m]?*wvec[k]?) @ W[N,K]^T (+bias)(+gelu)(+resid) ----------------
__global__ __launch_bounds__(256) void gemm_kernel(
    const float* __restrict__ A, int lda,
    const float* __restrict__ rs, const float* __restrict__ wvec,
    const float* __restrict__ W,
    const float* __restrict__ bias, const float* __restrict__ resid, int ldr,
    float* __restrict__ C, int ldc, int M, int N, int K, int act)
{
    const int BK = 16, ROWP = 68;
    __shared__ float As[BK][ROWP];
    __shared__ float Bs[BK][ROWP];
    int tid = threadIdx.x;
    int n0 = blockIdx.x * 64, m0 = blockIdx.y * 64;
    int lr = tid >> 2;          // 0..63
    int lk = (tid & 3) * 4;     // 0,4,8,12
    int row0 = (tid >> 4) * 4, col0 = (tid & 15) * 4;
    float acc[4][4] = {};

    for (int k0 = 0; k0 < K; k0 += BK){
        float4 av = *reinterpret_cast<const float4*>(&A[(size_t)(m0 + lr) * lda + k0 + lk]);
        float sc = rs ? rs[m0 + lr] : 1.f;
        if (wvec){
            const float4 wv4 = *reinterpret_cast<const float4*>(&wvec[k0 + lk]);
            av.x *= wv4.x; av.y *= wv4.y; av.z *= wv4.z; av.w *= wv4.w;
        }
        As[lk + 0][lr] = av.x * sc; As[lk + 1][lr] = av.y * sc;
        As[lk + 2][lr] = av.z * sc; As[lk + 3][lr] = av.w * sc;
        int n = n0 + lr;
        float4 wv = make_float4(0.f, 0.f, 0.f, 0.f);
        if (n < N) wv = *reinterpret_cast<const float4*>(&W[(size_t)n * K + k0 + lk]);
        Bs[lk + 0][lr] = wv.x; Bs[lk + 1][lr] = wv.y; Bs[lk + 2][lr] = wv.z; Bs[lk + 3][lr] = wv.w;
        __syncthreads();
        #pragma unroll
        for (int k = 0; k < BK; k++){
            float a0 = As[k][row0 + 0], a1 = As[k][row0 + 1], a2 = As[k][row0 + 2], a3 = As[k][row0 + 3];
            float b0 = Bs[k][col0 + 0], b1 = Bs[k][col0 + 1], b2 = Bs[k][col0 + 2], b3 = Bs[k][col0 + 3];
            acc[0][0] += a0 * b0; acc[0][1] += a0 * b1; acc[0][2] += a0 * b2; acc[0][3] += a0 * b3;
            acc[1][0] += a1 * b0; acc[1][1] += a1 * b1; acc[1][2] += a1 * b2; acc[1][3] += a1 * b3;
            acc[2][0] += a2 * b0; acc[2][1] += a2 * b1; acc[2][2] += a2 * b2; acc[2][3] += a2 * b3;
            acc[3][0] += a3 * b0; acc[3][1] += a3 * b1; acc[3][2] += a3 * b2; acc[3][3] += a3 * b3;
        }
        __syncthreads();
    }

    #pragma unroll
    for (int i = 0; i < 4; i++){
        int m = m0 + row0 + i;
        #pragma unroll
        for (int j = 0; j < 4; j++){
            int n = n0 + col0 + j;
            if (n < N){
                float c = acc[i][j];
                if (bias) c += bias[n];
                if (act == 1) c = 0.5f * c * (1.f + erff(c * 0.70710678118654752f));
                if (resid) c += resid[(size_t)m * ldr + n];
                C[(size_t)m * ldc + n] = c;
            }
        }
    }
}

// ---------------- conv+silu for the 32 B/C channels -> BCc[ROWS][32] ----------------
__global__ void bcconv_kernel(const float* __restrict__ ZX, const float* __restrict__ cw,
                              const float* __restrict__ cb, float* __restrict__ BCc){
    int idx = blockIdx.x * blockDim.x + threadIdx.x;
    if (idx >= ROWS_ * 32) return;
    int j = idx & 31;
    int row = idx >> 5;
    int l = row & (L_ - 1);
    float acc = cb[DI_ + j];
    #pragma unroll
    for (int k = 0; k < 4; k++){
        int lt = l + k - 3;
        if (lt >= 0)
            acc += ZX[(size_t)(row + k - 3) * DPROJ_ + (DI_ + DI_) + j] * cw[(DI_ + j) * 4 + k];
    }
    BCc[idx] = acc / (1.f + expf(-acc));
}

// ---------------- dt = softplus(raw + dt_bias); dA = exp(-exp(A_log)*dt) ----------------
__global__ void dt_kernel(const float* __restrict__ ZX, const float* __restrict__ dtb,
                          const float* __restrict__ Alog, float* __restrict__ DT,
                          float* __restrict__ DA){
    int idx = blockIdx.x * blockDim.x + threadIdx.x;
    if (idx >= ROWS_ * NH_) return;
    int h = idx & 15; int row = idx >> 4;
    float v = ZX[(size_t)row * DPROJ_ + (DPROJ_ - NH_) + h] + dtb[h];
    float dtv = (v > 20.f) ? v : log1pf(expf(v));
    DT[idx] = dtv;
    DA[idx] = expf(-expf(Alog[h]) * dtv);
}

// ======== chunked SSM scan (3 phases) ========
// blk id = b*(NH*NCHUNK) + h*NCHUNK + c ; lane = p (head dim)

// ---- phase A: per-chunk local scan (init 0); saves local end-state, dA product, conv window ----
__global__ __launch_bounds__(64) void scanA_kernel(const float* __restrict__ ZX,
                                                   const float* __restrict__ BCc,
                                                   const float* __restrict__ DT,
                                                   const float* __restrict__ DA,
                                                   const float* __restrict__ cw,
                                                   const float* __restrict__ cb,
                                                   float* __restrict__ SCH,
                                                   float* __restrict__ PCH,
                                                   float* __restrict__ XWIN){
    int blk = blockIdx.x;
    int c = blk & (NCHUNK_ - 1); int h = (blk >> 4) & (NH_ - 1); int b = blk >> 8;
    int p = threadIdx.x;
    int ch = h * HD_ + p;
    float cw0 = cw[ch * 4 + 0], cw1 = cw[ch * 4 + 1], cw2 = cw[ch * 4 + 2], cw3 = cw[ch * 4 + 3];
    float cbc = cb[ch];
    size_t colx = (size_t)DI_ + ch;
    int t0 = c * CLEN_;                       // local time within batch b
    float w0 = 0.f, w1 = 0.f, w2 = 0.f;
    if (c > 0){
        w0 = ZX[(size_t)(b * L_ + t0 - 3) * DPROJ_ + colx];
        w1 = ZX[(size_t)(b * L_ + t0 - 2) * DPROJ_ + colx];
        w2 = ZX[(size_t)(b * L_ + t0 - 1) * DPROJ_ + colx];
    }
    float* xw = XWIN + (size_t)blk * (3 * 64);
    xw[0 * 64 + p] = w0; xw[1 * 64 + p] = w1; xw[2 * 64 + p] = w2;

    float s[16];
    #pragma unroll
    for (int n = 0; n < 16; n++) s[n] = 0.f;
    float pprod = 1.f;

    for (int tt = 0; tt < CLEN_; tt++){
        int row = b * L_ + t0 + tt;
        size_t rowoff = (size_t)row * DPROJ_;
        float cur = ZX[rowoff + colx];
        float pre = cbc + cw0 * w0 + cw1 * w1 + cw2 * w2 + cw3 * cur;
        float xc = pre / (1.f + expf(-pre));
        w0 = w1; w1 = w2; w2 = cur;
        float dtv = DT[row * NH_ + h];
        float dav = DA[row * NH_ + h];
        pprod *= dav;
        float bc[16];
        const float4* bp = reinterpret_cast<const float4*>(BCc + (size_t)row * 32);
        #pragma unroll
        for (int i = 0; i < 4; i++){
            float4 v = bp[i];
            bc[4 * i + 0] = v.x; bc[4 * i + 1] = v.y; bc[4 * i + 2] = v.z; bc[4 * i + 3] = v.w;
        }
        float coef = dtv * xc;
        #pragma unroll
        for (int n = 0; n < 16; n++)
            s[n] = fmaf(s[n], dav, coef * bc[n]);
    }
    float* sc = SCH + (size_t)blk * 1024 + p * 16;
    #pragma unroll
    for (int i = 0; i < 4; i++)
        *reinterpret_cast<float4*>(sc + 4 * i) = make_float4(s[4*i], s[4*i+1], s[4*i+2], s[4*i+3]);
    if (p == 0) PCH[blk] = pprod;
}

// ---- phase B: sequential combine over chunks; SCH becomes chunk-INITIAL states ----
__global__ __launch_bounds__(64) void scanB_kernel(float* __restrict__ SCH,
                                                   const float* __restrict__ PCH){
    int bh = blockIdx.x;            // b*NH + h
    int p = threadIdx.x;
    float s[16];
    #pragma unroll
    for (int n = 0; n < 16; n++) s[n] = 0.f;
    for (int c = 0; c < NCHUNK_; c++){
        int blk = bh * NCHUNK_ + c;
        float* sc = SCH + (size_t)blk * 1024 + p * 16;
        float loc[16];
        #pragma unroll
        for (int i = 0; i < 4; i++){
            float4 v = *reinterpret_cast<const float4*>(sc + 4 * i);
            loc[4*i] = v.x; loc[4*i+1] = v.y; loc[4*i+2] = v.z; loc[4*i+3] = v.w;
        }
        float P = PCH[blk];
        #pragma unroll
        for (int i = 0; i < 4; i++)
            *reinterpret_cast<float4*>(sc + 4 * i) = make_float4(s[4*i], s[4*i+1], s[4*i+2], s[4*i+3]);
        #pragma unroll
        for (int n = 0; n < 16; n++)
            s[n] = fmaf(P, s[n], loc[n]);
    }
}

// ---- phase C: re-run chunk from true initial state; write y over raw-x slot of ZX ----
__global__ __launch_bounds__(64) void scanC_kernel(float* __restrict__ ZX,
                                                   const float* __restrict__ BCc,
                                                   const float* __restrict__ DT,
                                                   const float* __restrict__ DA,
                                                   const float* __restrict__ cw,
                                                   const float* __restrict__ cb,
                                                   const float* __restrict__ Dh,
                                                   const float* __restrict__ SCH,
                                                   const float* __restrict__ XWIN){
    int blk = blockIdx.x;
    int c = blk & (NCHUNK_ - 1); int h = (blk >> 4) & (NH_ - 1); int b = blk >> 8;
    int p = threadIdx.x;
    int ch = h * HD_ + p;
    float cw0 = cw[ch * 4 + 0], cw1 = cw[ch * 4 + 1], cw2 = cw[ch * 4 + 2], cw3 = cw[ch * 4 + 3];
    float cbc = cb[ch];
    float Dv = Dh[h];
    size_t colx = (size_t)DI_ + ch;
    int t0 = c * CLEN_;
    const float* xw = XWIN + (size_t)blk * (3 * 64);
    float w0 = xw[0 * 64 + p], w1 = xw[1 * 64 + p], w2 = xw[2 * 64 + p];
    const float* sc = SCH + (size_t)blk * 1024 + p * 16;
    float s[16];
    #pragma unroll
    for (int i = 0; i < 4; i++){
        float4 v = *reinterpret_cast<const float4*>(sc + 4 * i);
        s[4*i] = v.x; s[4*i+1] = v.y; s[4*i+2] = v.z; s[4*i+3] = v.w;
    }

    for (int tt = 0; tt < CLEN_; tt++){
        int row = b * L_ + t0 + tt;
        size_t rowoff = (size_t)row * DPROJ_;
        float cur = ZX[rowoff + colx];
        float pre = cbc + cw0 * w0 + cw1 * w1 + cw2 * w2 + cw3 * cur;
        float xc = pre / (1.f + expf(-pre));
        w0 = w1; w1 = w2; w2 = cur;
        float dtv = DT[row * NH_ + h];
        float dav = DA[row * NH_ + h];
        float bc[32];
        const float4* bp = reinterpret_cast<const float4*>(BCc + (size_t)row * 32);
        #pragma unroll
        for (int i = 0; i < 8; i++){
            float4 v = bp[i];
            bc[4 * i + 0] = v.x; bc[4 * i + 1] = v.y; bc[4 * i + 2] = v.z; bc[4 * i + 3] = v.w;
        }
        float coef = dtv * xc;
        float y = 0.f;
        #pragma unroll
        for (int n = 0; n < 16; n++){
            s[n] = fmaf(s[n], dav, coef * bc[n]);
            y += s[n] * bc[16 + n];
        }
        ZX[rowoff + colx] = fmaf(Dv, xc, y);
    }
}

// ---------------- gated rmsnorm in place on ZX ----------------
__global__ void gatenorm_kernel(float* __restrict__ ZX, const float* __restrict__ gw){
    int row = blockIdx.x;
    float* zr = ZX + (size_t)row * DPROJ_;
    float* yr = zr + DI_;
    float ss = 0.f;
    for (int cc = threadIdx.x; cc < DI_; cc += blockDim.x){
        float z = zr[cc];
        float v = yr[cc] * (z / (1.f + expf(-z)));
        yr[cc] = v;
        ss += v * v;
    }
    float tot = block_reduce_sum(ss);
    float rsv = rsqrtf(tot / (float)DI_ + EPS_);
    for (int cc = threadIdx.x; cc < DI_; cc += blockDim.x)
        yr[cc] = yr[cc] * rsv * gw[cc];
}

extern "C" void kernel_launch(void* const* d_in, const int* in_sizes, int n_in,
                              void* d_out, int out_size, void* d_ws, size_t ws_size,
                              hipStream_t stream){
    const float* x_in        = (const float*)d_in[0];
    const float* in_proj_w   = (const float*)d_in[1];
    const float* conv_w      = (const float*)d_in[2];
    const float* conv_b      = (const float*)d_in[3];
    const float* dt_bias     = (const float*)d_in[4];
    const float* A_log       = (const float*)d_in[5];
    const float* D_ssm       = (const float*)d_in[6];
    const float* gnorm_w     = (const float*)d_in[7];
    const float* out_proj_w  = (const float*)d_in[8];
    const float* ffn_w1      = (const float*)d_in[9];
    const float* ffn_b1      = (const float*)d_in[10];
    const float* ffn_w2      = (const float*)d_in[11];
    const float* ffn_b2      = (const float*)d_in[12];
    const float* norm_mamba_w= (const float*)d_in[13];
    const float* norm_ffn_w  = (const float*)d_in[14];
    const float* final_norm_w= (const float*)d_in[15];

    // ---- workspace layout: ~46.8 MiB ----
    float* X   = (float*)d_ws;                        // ROWS*DM
    float* RS  = X   + (size_t)ROWS_ * DM_;           // ROWS
    float* BCc = RS  + ROWS_;                         // ROWS*32
    float* DT  = BCc + (size_t)ROWS_ * 32;            // ROWS*16
    float* DA  = DT  + (size_t)ROWS_ * NH_;           // ROWS*16
    float* SCH = DA  + (size_t)ROWS_ * NH_;           // 1024*1024 (chunk states)
    float* PCH = SCH + (size_t)1024 * 1024;           // 1024
    float* XWIN= PCH + 1024;                          // 1024*192
    float* ZX  = XWIN+ (size_t)1024 * 192;            // ROWS*DPROJ (reused as FFN hidden)

    const int NBLK = B_ * NH_ * NCHUNK_;              // 1024

    copy_kernel<<<(ROWS_ * DM_ + 255) / 256, 256, 0, stream>>>(x_in, X, ROWS_ * DM_);

    for (int l = 0; l < NLAYERS; l++){
        const float* cwl = conv_w + (size_t)l * CONVD_ * 4;
        const float* cbl = conv_b + (size_t)l * CONVD_;

        rowscale_kernel<<<ROWS_, 64, 0, stream>>>(X, RS);

        dim3 g1((DPROJ_ + 63) / 64, ROWS_ / 64);
        gemm_kernel<<<g1, 256, 0, stream>>>(X, DM_, RS, norm_mamba_w + l * DM_,
                                            in_proj_w + (size_t)l * DPROJ_ * DM_,
                                            nullptr, nullptr, 0,
                                            ZX, DPROJ_, ROWS_, DPROJ_, DM_, 0);

        bcconv_kernel<<<(ROWS_ * 32 + 255) / 256, 256, 0, stream>>>(ZX, cwl, cbl, BCc);

        dt_kernel<<<(ROWS_ * NH_ + 255) / 256, 256, 0, stream>>>(
            ZX, dt_bias + (size_t)l * NH_, A_log + (size_t)l * NH_, DT, DA);

        scanA_kernel<<<NBLK, 64, 0, stream>>>(ZX, BCc, DT, DA, cwl, cbl, SCH, PCH, XWIN);
        scanB_kernel<<<B_ * NH_, 64, 0, stream>>>(SCH, PCH);
        scanC_kernel<<<NBLK, 64, 0, stream>>>(ZX, BCc, DT, DA, cwl, cbl,
                                              D_ssm + (size_t)l * NH_, SCH, XWIN);

        gatenorm_kernel<<<ROWS_, 256, 0, stream>>>(ZX, gnorm_w + (size_t)l * DI_);

        dim3 g2((DM_ + 63) / 64, ROWS_ / 64);
        gemm_kernel<<<g2, 256, 0, stream>>>(ZX + DI_, DPROJ_, nullptr, nullptr,
                                            out_proj_w + (size_t)l * DM_ * DI_,
                                            nullptr, X, DM_,
                                            X, DM_, ROWS_, DM_, DI_, 0);

        rowscale_kernel<<<ROWS_, 64, 0, stream>>>(X, RS);

        dim3 g3((DFF_ + 63) / 64, ROWS_ / 64);
        gemm_kernel<<<g3, 256, 0, stream>>>(X, DM_, RS, norm_ffn_w + l * DM_,
                                            ffn_w1 + (size_t)l * DFF_ * DM_,
                                            ffn_b1 + (size_t)l * DFF_, nullptr, 0,
                                            ZX, DFF_, ROWS_, DFF_, DM_, 1);

        gemm_kernel<<<g2, 256, 0, stream>>>(ZX, DFF_, nullptr, nullptr,
                                            ffn_w2 + (size_t)l * DM_ * DFF_,
                                            ffn_b2 + (size_t)l * DM_, X, DM_,
                                            X, DM_, ROWS_, DM_, DFF_, 0);
    }

    finalnorm_kernel<<<ROWS_, 256, 0, stream>>>(X, final_norm_w, (float*)d_out);
}

// Round 10
// 3629.522 us; speedup vs baseline: 1.8825x; 1.1442x over previous
//
#include <hip/hip_runtime.h>
#include <hip/hip_bf16.h>

#define NLAYERS 6
#define B_ 4
#define L_ 1024
#define DM_ 512
#define DI_ 1024
#define NH_ 16
#define HD_ 64
#define NS_ 16
#define CONVD_ 1056
#define DPROJ_ 2096
#define DFF_ 2048
#define ROWS_ (B_*L_)
#define EPS_ 1e-5f
#define NCHUNK_ 16
#define CLEN_ 64

typedef __bf16 bfx8 __attribute__((ext_vector_type(8)));
typedef float f32x4 __attribute__((ext_vector_type(4)));

// ---------------- block reduction ----------------
__device__ __forceinline__ float block_reduce_sum(float v){
    __shared__ float sm[8];
    #pragma unroll
    for (int off = 32; off > 0; off >>= 1) v += __shfl_xor(v, off);
    int lane = threadIdx.x & 63, wid = threadIdx.x >> 6;
    if (lane == 0) sm[wid] = v;
    __syncthreads();
    if (threadIdx.x == 0){
        float t = 0.f;
        int nw = blockDim.x >> 6;
        for (int i = 0; i < nw; i++) t += sm[i];
        sm[0] = t;
    }
    __syncthreads();
    return sm[0];
}

// ---------------- copy x -> X ----------------
__global__ void copy_kernel(const float* __restrict__ x, float* __restrict__ X, int n){
    int i = blockIdx.x * blockDim.x + threadIdx.x;
    if (i < n) X[i] = x[i];
}

// ---------------- per-row inverse-RMS of X[ROWS][512] ----------------
__global__ __launch_bounds__(64) void rowscale_kernel(const float* __restrict__ X,
                                                      float* __restrict__ rs){
    int row = blockIdx.x, lane = threadIdx.x;
    const float* xr = X + (size_t)row * DM_;
    float ss = 0.f;
    #pragma unroll
    for (int i = 0; i < DM_ / 64; i++){ float v = xr[lane + 64 * i]; ss += v * v; }
    #pragma unroll
    for (int off = 32; off > 0; off >>= 1) ss += __shfl_xor(ss, off);
    if (lane == 0) rs[row] = rsqrtf(ss / (float)DM_ + EPS_);
}

// ---------------- final rmsnorm -> f32 out ----------------
__global__ void finalnorm_kernel(const float* __restrict__ in, const float* __restrict__ w,
                                 float* __restrict__ out){
    int row = blockIdx.x;
    const float* xr = in + (size_t)row * DM_;
    float ss = 0.f;
    for (int c = threadIdx.x; c < DM_; c += blockDim.x){ float v = xr[c]; ss += v * v; }
    float tot = block_reduce_sum(ss);
    float rsv = rsqrtf(tot / (float)DM_ + EPS_);
    float* orow = out + (size_t)row * DM_;
    for (int c = threadIdx.x; c < DM_; c += blockDim.x)
        orow[c] = xr[c] * rsv * w[c];
}

// ---------------- split-convert A: X(f32,lda) [*rs[m]] [*wv[k]] -> A2[M][2K] bf16 (hi|lo) ----------------
__global__ void convA_kernel(const float* __restrict__ X, int lda,
                             const float* __restrict__ rs, const float* __restrict__ wv,
                             __bf16* __restrict__ A2, int M, int K){
    int idx = blockIdx.x * blockDim.x + threadIdx.x;
    if (idx >= M * K) return;
    int m = idx / K, k = idx - m * K;
    float a = X[(size_t)m * lda + k];
    if (rs) a *= rs[m];
    if (wv) a *= wv[k];
    __bf16 hi = (__bf16)a;
    A2[(size_t)m * (2 * K) + k] = hi;
    A2[(size_t)m * (2 * K) + K + k] = (__bf16)(a - (float)hi);
}

// ---------------- split-convert W: W(f32)[N][K] -> W2[N][3K] bf16 (hi|lo|hi) ----------------
__global__ void convW_kernel(const float* __restrict__ W, __bf16* __restrict__ W2,
                             int N, int K){
    int idx = blockIdx.x * blockDim.x + threadIdx.x;
    if (idx >= N * K) return;
    int n = idx / K, k = idx - n * K;
    float w = W[(size_t)n * K + k];
    __bf16 hi = (__bf16)w;
    __bf16 lo = (__bf16)(w - (float)hi);
    size_t ro = (size_t)n * (3 * K);
    W2[ro + k] = hi; W2[ro + K + k] = lo; W2[ro + 2 * K + k] = hi;
}

// ---------------- split-bf16 MFMA GEMM: C = A2 x W2^T over K'=3K ----------------
// A2[M][2K] (hi|lo), W2[N][3K] (hi|lo|hi); A column remap pairs: hi*hi + hi*lo + lo*hi.
// Epilogue: +bias, gelu(act), +resid(ldr); writes f32 Cf(ldc) or bf16 split Cs (halfwidth csK).
__global__ __launch_bounds__(256) void gemm_mfma_kernel(
    const __bf16* __restrict__ A2, const __bf16* __restrict__ W2,
    const float* __restrict__ bias, const float* __restrict__ resid, int ldr,
    float* __restrict__ Cf, int ldc, __bf16* __restrict__ Cs, int csK,
    int M, int N, int K, int act)
{
    __shared__ __attribute__((aligned(16))) __bf16 As[128 * 32];
    __shared__ __attribute__((aligned(16))) __bf16 Ws[128 * 32];
    int tid = threadIdx.x;
    int n0 = blockIdx.x * 128, m0 = blockIdx.y * 128;
    int wv = tid >> 6, lane = tid & 63;
    int wm = (wv >> 1) * 64, wn = (wv & 1) * 64;
    int lm = lane & 15, quad = lane >> 4;

    f32x4 acc[4][4] = {};
    const int krows = 3 * K;

    for (int k0 = 0; k0 < krows; k0 += 32){
        int ak0 = (k0 < K) ? k0 : (k0 - K);   // hi,hi,lo pairing with W's hi,lo,hi
        #pragma unroll
        for (int u = 0; u < 2; u++){
            int c = tid + u * 256;            // chunk 0..511 (16B each)
            int r = c >> 2, sg = (c & 3) * 8; // row 0..127, col seg (bf16 elems)
            *reinterpret_cast<uint4*>(&As[r * 32 + sg]) =
                *reinterpret_cast<const uint4*>(&A2[(size_t)(m0 + r) * (2 * K) + ak0 + sg]);
            int n = n0 + r;
            uint4 wvd = make_uint4(0u, 0u, 0u, 0u);
            if (n < N)
                wvd = *reinterpret_cast<const uint4*>(&W2[(size_t)n * (3 * K) + k0 + sg]);
            *reinterpret_cast<uint4*>(&Ws[r * 32 + sg]) = wvd;
        }
        __syncthreads();
        bfx8 af[4], bfr[4];
        #pragma unroll
        for (int i = 0; i < 4; i++)
            af[i] = *reinterpret_cast<const bfx8*>(&As[(wm + i * 16 + lm) * 32 + quad * 8]);
        #pragma unroll
        for (int j = 0; j < 4; j++)
            bfr[j] = *reinterpret_cast<const bfx8*>(&Ws[(wn + j * 16 + lm) * 32 + quad * 8]);
        #pragma unroll
        for (int i = 0; i < 4; i++)
            #pragma unroll
            for (int j = 0; j < 4; j++)
                acc[i][j] = __builtin_amdgcn_mfma_f32_16x16x32_bf16(af[i], bfr[j], acc[i][j], 0, 0, 0);
        __syncthreads();
    }

    #pragma unroll
    for (int i = 0; i < 4; i++){
        #pragma unroll
        for (int j = 0; j < 4; j++){
            int n = n0 + wn + j * 16 + lm;
            if (n < N){
                #pragma unroll
                for (int r = 0; r < 4; r++){
                    int m = m0 + wm + i * 16 + quad * 4 + r;
                    float c = acc[i][j][r];
                    if (bias) c += bias[n];
                    if (act == 1) c = 0.5f * c * (1.f + erff(c * 0.70710678118654752f));
                    if (resid) c += resid[(size_t)m * ldr + n];
                    if (Cf) Cf[(size_t)m * ldc + n] = c;
                    else {
                        __bf16 hi = (__bf16)c;
                        Cs[(size_t)m * (2 * csK) + n] = hi;
                        Cs[(size_t)m * (2 * csK) + csK + n] = (__bf16)(c - (float)hi);
                    }
                }
            }
        }
    }
}

// ---------------- conv+silu for the 32 B/C channels -> BCc[ROWS][32] ----------------
__global__ void bcconv_kernel(const float* __restrict__ ZX, const float* __restrict__ cw,
                              const float* __restrict__ cb, float* __restrict__ BCc){
    int idx = blockIdx.x * blockDim.x + threadIdx.x;
    if (idx >= ROWS_ * 32) return;
    int j = idx & 31;
    int row = idx >> 5;
    int l = row & (L_ - 1);
    float acc = cb[DI_ + j];
    #pragma unroll
    for (int k = 0; k < 4; k++){
        int lt = l + k - 3;
        if (lt >= 0)
            acc += ZX[(size_t)(row + k - 3) * DPROJ_ + (DI_ + DI_) + j] * cw[(DI_ + j) * 4 + k];
    }
    BCc[idx] = acc / (1.f + expf(-acc));
}

// ---------------- dt = softplus(raw + dt_bias); dA = exp(-exp(A_log)*dt) ----------------
__global__ void dt_kernel(const float* __restrict__ ZX, const float* __restrict__ dtb,
                          const float* __restrict__ Alog, float* __restrict__ DT,
                          float* __restrict__ DA){
    int idx = blockIdx.x * blockDim.x + threadIdx.x;
    if (idx >= ROWS_ * NH_) return;
    int h = idx & 15; int row = idx >> 4;
    float v = ZX[(size_t)row * DPROJ_ + (DPROJ_ - NH_) + h] + dtb[h];
    float dtv = (v > 20.f) ? v : log1pf(expf(v));
    DT[idx] = dtv;
    DA[idx] = expf(-expf(Alog[h]) * dtv);
}

// ======== chunked SSM scan (3 phases); blk = b*(NH*NCHUNK)+h*NCHUNK+c ; lane = p ========
__global__ __launch_bounds__(64) void scanA_kernel(const float* __restrict__ ZX,
                                                   const float* __restrict__ BCc,
                                                   const float* __restrict__ DT,
                                                   const float* __restrict__ DA,
                                                   const float* __restrict__ cw,
                                                   const float* __restrict__ cb,
                                                   float* __restrict__ SCH,
                                                   float* __restrict__ PCH,
                                                   float* __restrict__ XWIN){
    int blk = blockIdx.x;
    int c = blk & (NCHUNK_ - 1); int h = (blk >> 4) & (NH_ - 1); int b = blk >> 8;
    int p = threadIdx.x;
    int ch = h * HD_ + p;
    float cw0 = cw[ch * 4 + 0], cw1 = cw[ch * 4 + 1], cw2 = cw[ch * 4 + 2], cw3 = cw[ch * 4 + 3];
    float cbc = cb[ch];
    size_t colx = (size_t)DI_ + ch;
    int t0 = c * CLEN_;
    float w0 = 0.f, w1 = 0.f, w2 = 0.f;
    if (c > 0){
        w0 = ZX[(size_t)(b * L_ + t0 - 3) * DPROJ_ + colx];
        w1 = ZX[(size_t)(b * L_ + t0 - 2) * DPROJ_ + colx];
        w2 = ZX[(size_t)(b * L_ + t0 - 1) * DPROJ_ + colx];
    }
    float* xw = XWIN + (size_t)blk * (3 * 64);
    xw[0 * 64 + p] = w0; xw[1 * 64 + p] = w1; xw[2 * 64 + p] = w2;

    float s[16];
    #pragma unroll
    for (int n = 0; n < 16; n++) s[n] = 0.f;
    float pprod = 1.f;

    for (int tt = 0; tt < CLEN_; tt++){
        int row = b * L_ + t0 + tt;
        size_t rowoff = (size_t)row * DPROJ_;
        float cur = ZX[rowoff + colx];
        float pre = cbc + cw0 * w0 + cw1 * w1 + cw2 * w2 + cw3 * cur;
        float xc = pre / (1.f + expf(-pre));
        w0 = w1; w1 = w2; w2 = cur;
        float dtv = DT[row * NH_ + h];
        float dav = DA[row * NH_ + h];
        pprod *= dav;
        float bc[16];
        const float4* bp = reinterpret_cast<const float4*>(BCc + (size_t)row * 32);
        #pragma unroll
        for (int i = 0; i < 4; i++){
            float4 v = bp[i];
            bc[4 * i + 0] = v.x; bc[4 * i + 1] = v.y; bc[4 * i + 2] = v.z; bc[4 * i + 3] = v.w;
        }
        float coef = dtv * xc;
        #pragma unroll
        for (int n = 0; n < 16; n++)
            s[n] = fmaf(s[n], dav, coef * bc[n]);
    }
    float* sc = SCH + (size_t)blk * 1024 + p * 16;
    #pragma unroll
    for (int i = 0; i < 4; i++)
        *reinterpret_cast<float4*>(sc + 4 * i) = make_float4(s[4*i], s[4*i+1], s[4*i+2], s[4*i+3]);
    if (p == 0) PCH[blk] = pprod;
}

__global__ __launch_bounds__(64) void scanB_kernel(float* __restrict__ SCH,
                                                   const float* __restrict__ PCH){
    int bh = blockIdx.x;
    int p = threadIdx.x;
    float s[16];
    #pragma unroll
    for (int n = 0; n < 16; n++) s[n] = 0.f;
    for (int c = 0; c < NCHUNK_; c++){
        int blk = bh * NCHUNK_ + c;
        float* sc = SCH + (size_t)blk * 1024 + p * 16;
        float loc[16];
        #pragma unroll
        for (int i = 0; i < 4; i++){
            float4 v = *reinterpret_cast<const float4*>(sc + 4 * i);
            loc[4*i] = v.x; loc[4*i+1] = v.y; loc[4*i+2] = v.z; loc[4*i+3] = v.w;
        }
        float P = PCH[blk];
        #pragma unroll
        for (int i = 0; i < 4; i++)
            *reinterpret_cast<float4*>(sc + 4 * i) = make_float4(s[4*i], s[4*i+1], s[4*i+2], s[4*i+3]);
        #pragma unroll
        for (int n = 0; n < 16; n++)
            s[n] = fmaf(P, s[n], loc[n]);
    }
}

__global__ __launch_bounds__(64) void scanC_kernel(float* __restrict__ ZX,
                                                   const float* __restrict__ BCc,
                                                   const float* __restrict__ DT,
                                                   const float* __restrict__ DA,
                                                   const float* __restrict__ cw,
                                                   const float* __restrict__ cb,
                                                   const float* __restrict__ Dh,
                                                   const float* __restrict__ SCH,
                                                   const float* __restrict__ XWIN){
    int blk = blockIdx.x;
    int c = blk & (NCHUNK_ - 1); int h = (blk >> 4) & (NH_ - 1); int b = blk >> 8;
    int p = threadIdx.x;
    int ch = h * HD_ + p;
    float cw0 = cw[ch * 4 + 0], cw1 = cw[ch * 4 + 1], cw2 = cw[ch * 4 + 2], cw3 = cw[ch * 4 + 3];
    float cbc = cb[ch];
    float Dv = Dh[h];
    size_t colx = (size_t)DI_ + ch;
    int t0 = c * CLEN_;
    const float* xw = XWIN + (size_t)blk * (3 * 64);
    float w0 = xw[0 * 64 + p], w1 = xw[1 * 64 + p], w2 = xw[2 * 64 + p];
    const float* sc = SCH + (size_t)blk * 1024 + p * 16;
    float s[16];
    #pragma unroll
    for (int i = 0; i < 4; i++){
        float4 v = *reinterpret_cast<const float4*>(sc + 4 * i);
        s[4*i] = v.x; s[4*i+1] = v.y; s[4*i+2] = v.z; s[4*i+3] = v.w;
    }

    for (int tt = 0; tt < CLEN_; tt++){
        int row = b * L_ + t0 + tt;
        size_t rowoff = (size_t)row * DPROJ_;
        float cur = ZX[rowoff + colx];
        float pre = cbc + cw0 * w0 + cw1 * w1 + cw2 * w2 + cw3 * cur;
        float xc = pre / (1.f + expf(-pre));
        w0 = w1; w1 = w2; w2 = cur;
        float dtv = DT[row * NH_ + h];
        float dav = DA[row * NH_ + h];
        float bc[32];
        const float4* bp = reinterpret_cast<const float4*>(BCc + (size_t)row * 32);
        #pragma unroll
        for (int i = 0; i < 8; i++){
            float4 v = bp[i];
            bc[4 * i + 0] = v.x; bc[4 * i + 1] = v.y; bc[4 * i + 2] = v.z; bc[4 * i + 3] = v.w;
        }
        float coef = dtv * xc;
        float y = 0.f;
        #pragma unroll
        for (int n = 0; n < 16; n++){
            s[n] = fmaf(s[n], dav, coef * bc[n]);
            y += s[n] * bc[16 + n];
        }
        ZX[rowoff + colx] = fmaf(Dv, xc, y);
    }
}

// ---------------- gated rmsnorm in place on ZX ----------------
__global__ void gatenorm_kernel(float* __restrict__ ZX, const float* __restrict__ gw){
    int row = blockIdx.x;
    float* zr = ZX + (size_t)row * DPROJ_;
    float* yr = zr + DI_;
    float ss = 0.f;
    for (int cc = threadIdx.x; cc < DI_; cc += blockDim.x){
        float z = zr[cc];
        float v = yr[cc] * (z / (1.f + expf(-z)));
        yr[cc] = v;
        ss += v * v;
    }
    float tot = block_reduce_sum(ss);
    float rsv = rsqrtf(tot / (float)DI_ + EPS_);
    for (int cc = threadIdx.x; cc < DI_; cc += blockDim.x)
        yr[cc] = yr[cc] * rsv * gw[cc];
}

extern "C" void kernel_launch(void* const* d_in, const int* in_sizes, int n_in,
                              void* d_out, int out_size, void* d_ws, size_t ws_size,
                              hipStream_t stream){
    const float* x_in        = (const float*)d_in[0];
    const float* in_proj_w   = (const float*)d_in[1];
    const float* conv_w      = (const float*)d_in[2];
    const float* conv_b      = (const float*)d_in[3];
    const float* dt_bias     = (const float*)d_in[4];
    const float* A_log       = (const float*)d_in[5];
    const float* D_ssm       = (const float*)d_in[6];
    const float* gnorm_w     = (const float*)d_in[7];
    const float* out_proj_w  = (const float*)d_in[8];
    const float* ffn_w1      = (const float*)d_in[9];
    const float* ffn_b1      = (const float*)d_in[10];
    const float* ffn_w2      = (const float*)d_in[11];
    const float* ffn_b2      = (const float*)d_in[12];
    const float* norm_mamba_w= (const float*)d_in[13];
    const float* norm_ffn_w  = (const float*)d_in[14];
    const float* final_norm_w= (const float*)d_in[15];

    // ---- workspace layout: ~68.7 MiB (<= R2-proven 85.7 MiB) ----
    float* X    = (float*)d_ws;                       // 2,097,152 f
    float* RS   = X    + 2097152;                     // 4096
    float* BCc  = RS   + 4096;                        // 131072
    float* DT   = BCc  + 131072;                      // 65536
    float* DA   = DT   + 65536;                       // 65536
    float* SCH  = DA   + 65536;                       // 1,048,576
    float* PCH  = SCH  + 1048576;                     // 1024
    float* XWIN = PCH  + 1024;                        // 196,608
    __bf16* A2  = (__bf16*)(XWIN + 196608);           // 8,388,608 bf16 (max M x 2K, K=1024)
    __bf16* W2  = A2 + 8388608;                       // 3,219,520 bf16 (max N x 3K)
    float* ZX   = (float*)(W2 + 3219520);             // 4096 x 2096 f32 (also H-split region)
    __bf16* Hs  = (__bf16*)ZX;                        // 4096 x 4096 bf16 (ffn hidden, hi|lo)

    const int NBLK = B_ * NH_ * NCHUNK_;              // 1024

    copy_kernel<<<(ROWS_ * DM_ + 255) / 256, 256, 0, stream>>>(x_in, X, ROWS_ * DM_);

    for (int l = 0; l < NLAYERS; l++){
        const float* cwl = conv_w + (size_t)l * CONVD_ * 4;
        const float* cbl = conv_b + (size_t)l * CONVD_;

        // ---- mamba: fused rmsnorm into A-conversion, then MFMA in_proj ----
        rowscale_kernel<<<ROWS_, 64, 0, stream>>>(X, RS);
        convA_kernel<<<(ROWS_ * DM_ + 255) / 256, 256, 0, stream>>>(
            X, DM_, RS, norm_mamba_w + (size_t)l * DM_, A2, ROWS_, DM_);
        convW_kernel<<<(DPROJ_ * DM_ + 255) / 256, 256, 0, stream>>>(
            in_proj_w + (size_t)l * DPROJ_ * DM_, W2, DPROJ_, DM_);
        {
            dim3 g((DPROJ_ + 127) / 128, ROWS_ / 128);
            gemm_mfma_kernel<<<g, 256, 0, stream>>>(A2, W2, nullptr, nullptr, 0,
                                                    ZX, DPROJ_, nullptr, 0,
                                                    ROWS_, DPROJ_, DM_, 0);
        }

        bcconv_kernel<<<(ROWS_ * 32 + 255) / 256, 256, 0, stream>>>(ZX, cwl, cbl, BCc);
        dt_kernel<<<(ROWS_ * NH_ + 255) / 256, 256, 0, stream>>>(
            ZX, dt_bias + (size_t)l * NH_, A_log + (size_t)l * NH_, DT, DA);

        scanA_kernel<<<NBLK, 64, 0, stream>>>(ZX, BCc, DT, DA, cwl, cbl, SCH, PCH, XWIN);
        scanB_kernel<<<B_ * NH_, 64, 0, stream>>>(SCH, PCH);
        scanC_kernel<<<NBLK, 64, 0, stream>>>(ZX, BCc, DT, DA, cwl, cbl,
                                              D_ssm + (size_t)l * NH_, SCH, XWIN);

        gatenorm_kernel<<<ROWS_, 256, 0, stream>>>(ZX, gnorm_w + (size_t)l * DI_);

        // ---- out_proj (MFMA, resid into X) ----
        convA_kernel<<<(ROWS_ * DI_ + 255) / 256, 256, 0, stream>>>(
            ZX + DI_, DPROJ_, nullptr, nullptr, A2, ROWS_, DI_);
        convW_kernel<<<(DM_ * DI_ + 255) / 256, 256, 0, stream>>>(
            out_proj_w + (size_t)l * DM_ * DI_, W2, DM_, DI_);
        {
            dim3 g((DM_ + 127) / 128, ROWS_ / 128);
            gemm_mfma_kernel<<<g, 256, 0, stream>>>(A2, W2, nullptr, X, DM_,
                                                    X, DM_, nullptr, 0,
                                                    ROWS_, DM_, DI_, 0);
        }

        // ---- ffn: norm->conv, ffn1 emits bf16 split hidden, ffn2 resid into X ----
        rowscale_kernel<<<ROWS_, 64, 0, stream>>>(X, RS);
        convA_kernel<<<(ROWS_ * DM_ + 255) / 256, 256, 0, stream>>>(
            X, DM_, RS, norm_ffn_w + (size_t)l * DM_, A2, ROWS_, DM_);
        convW_kernel<<<(DFF_ * DM_ + 255) / 256, 256, 0, stream>>>(
            ffn_w1 + (size_t)l * DFF_ * DM_, W2, DFF_, DM_);
        {
            dim3 g((DFF_ + 127) / 128, ROWS_ / 128);
            gemm_mfma_kernel<<<g, 256, 0, stream>>>(A2, W2, ffn_b1 + (size_t)l * DFF_,
                                                    nullptr, 0, nullptr, 0,
                                                    Hs, DFF_, ROWS_, DFF_, DM_, 1);
        }
        convW_kernel<<<(DM_ * DFF_ + 255) / 256, 256, 0, stream>>>(
            ffn_w2 + (size_t)l * DM_ * DFF_, W2, DM_, DFF_);
        {
            dim3 g((DM_ + 127) / 128, ROWS_ / 128);
            gemm_mfma_kernel<<<g, 256, 0, stream>>>(Hs, W2, ffn_b2 + (size_t)l * DM_,
                                                    X, DM_, X, DM_, nullptr, 0,
                                                    ROWS_, DM_, DFF_, 0);
        }
    }

    finalnorm_kernel<<<ROWS_, 256, 0, stream>>>(X, final_norm_w, (float*)d_out);
}